// Round 8
// baseline (205.741 us; speedup 1.0000x reference)
//
#include <hip/hip_runtime.h>
#include <math.h>

#define BATCH 2
#define SEQ   2048
#define HID   1024
#define NHEAD 16
#define HDIM  64
#define MTOT  (BATCH * SEQ)   // 4096
#define QKVN  (3 * HID)       // 3072
#define HBUF  ((size_t)BATCH * NHEAD * SEQ * HDIM)   // elems per q/k/vT buf

typedef _Float16 f16x8 __attribute__((ext_vector_type(8)));
typedef _Float16 f16x4 __attribute__((ext_vector_type(4)));
typedef float    f32x4 __attribute__((ext_vector_type(4)));

#define MFMA16(a, b, c) __builtin_amdgcn_mfma_f32_16x16x32_f16((a), (b), (c), 0, 0, 0)

#define GLDS16(gp, lp) __builtin_amdgcn_global_load_lds( \
    (const __attribute__((address_space(1))) void*)(gp), \
    (__attribute__((address_space(3))) void*)(lp), 16, 0, 0)

#if __has_builtin(__builtin_amdgcn_exp2f)
#define EXP2F(x) __builtin_amdgcn_exp2f(x)
#else
#define EXP2F(x) exp2f(x)
#endif

#define SCALE2 0.18033688011f     // 0.125 * log2(e)
#define MASK2  -14426.950408f     // -10000 * log2(e)  -> exp2 == 0 exactly
#define BIAS2  -4.0f              // headroom shift; cancels in normalization

// two-bit GEMM chunk swizzle key: rows a, a+4, a+8, a+12 get distinct chunks
#define SWZ4(row) (((row) & 3) ^ (((row) >> 2) & 3))

// ---------------------------------------------------------------------------
// Fused prep:
//   blocks [0,2048):    hs fp32 -> fp16 with GEMM-A chunk swizzle (c ^= SWZ4(m))
//   blocks [2048,6144): Wqkv/Wd fp32 [K][N] -> fp16 [N][K] + B-operand swizzle
// ---------------------------------------------------------------------------
__global__ __launch_bounds__(256) void prep_kernel(
    const float* __restrict__ hs, const float* __restrict__ Wqkv,
    const float* __restrict__ Wd, _Float16* __restrict__ A_h,
    _Float16* __restrict__ outQ, _Float16* __restrict__ outD)
{
    __shared__ _Float16 T[32][36];
    const int gid = blockIdx.x;
    const int tid = threadIdx.x;
    if (gid < 2048) {
        const int ci = gid * 256 + tid;
        const int m = ci >> 7, cc = ci & 127;
        const int g = cc >> 2, c = cc & 3;
        const float* src = hs + (size_t)m * 1024 + cc * 8;
        f16x8 o;
#pragma unroll
        for (int j = 0; j < 8; ++j) o[j] = (_Float16)src[j];
        *(f16x8*)(A_h + (size_t)m * 1024 + g * 32 + ((c ^ SWZ4(m)) << 3)) = o;
        return;
    }
    const int tb = gid - 2048;
    const int bx = tb & 127, k0 = (tb >> 7) * 32;
    const float* in;
    _Float16* out;
    int N, n0;
    if (bx < 96) { in = Wqkv; out = outQ; N = QKVN; n0 = bx * 32; }
    else         { in = Wd;   out = outD; N = HID;  n0 = (bx - 96) * 32; }
    {
        const int r = tid >> 3, c4 = (tid & 7) * 4;
        float4 v = *(const float4*)(in + (size_t)(k0 + r) * N + n0 + c4);
        T[r][c4 + 0] = (_Float16)v.x;
        T[r][c4 + 1] = (_Float16)v.y;
        T[r][c4 + 2] = (_Float16)v.z;
        T[r][c4 + 3] = (_Float16)v.w;
    }
    __syncthreads();
    {
        const int nn = tid >> 3, k4 = (tid & 7) * 4;
        const int n = n0 + nn;
        f16x4 o;
        o[0] = T[k4 + 0][nn]; o[1] = T[k4 + 1][nn];
        o[2] = T[k4 + 2][nn]; o[3] = T[k4 + 3][nn];
        const int pos = ((k4 >> 3) ^ SWZ4(n)), half = (k4 >> 2) & 1;
        *(f16x4*)(out + (size_t)n * 1024 + k0 + pos * 8 + half * 4) = o;
    }
}

// ---------------------------------------------------------------------------
// MFMA fp16 GEMM, TMx128xBK32. Fragment reads use the two-bit SWZ4 swizzle
// (conflict-free b128). LDS-bounce epilogues sized to the K-loop footprint:
// EPI=0 (TM=128, SMEM 18.4K): 2-pass 32-row bounce; q plain, k chunk^(s&7),
//                             v staged transposed -> swizzled vT directly.
// EPI=1 (TM=64, SMEM 17.4K):  per-i 16-row fp32 bounce, coalesced float4.
// ---------------------------------------------------------------------------
template<int EPI, int TM>
__global__ __launch_bounds__(256) void mfma_gemm(
    const _Float16* __restrict__ A, const _Float16* __restrict__ Bt,
    const float* __restrict__ bias, void* __restrict__ Cout,
    int M, int N, int K)
{
    constexpr int SMEM_BYTES = (EPI == 0) ? 18432 : 17408;
    __shared__ __align__(16) char SMEM[SMEM_BYTES];
    _Float16* As = (_Float16*)SMEM;
    _Float16* Bs = As + TM * 32;
    constexpr int TI = TM / 32;
    constexpr int AR = TM / 4;

    const int tid = threadIdx.x;
    const int w = tid >> 6, l = tid & 63;
    const int a = l & 15, q4 = l >> 4;
    const int m0 = blockIdx.y * TM, n0 = blockIdx.x * 128;
    const int wm = (w >> 1) * (TM / 2), wn = (w & 1) * 64;

    f32x4 acc[TI][4];
#pragma unroll
    for (int i = 0; i < TI; ++i)
#pragma unroll
        for (int j = 0; j < 4; ++j) acc[i][j] = (f32x4){0.f, 0.f, 0.f, 0.f};

    const _Float16* gA = A + (size_t)(m0 + w * AR + (l >> 2)) * K + (l & 3) * 8;
    const _Float16* gB = Bt + (size_t)(n0 + w * 32 + (l >> 2)) * K + (l & 3) * 8;
    _Float16* sA = As + w * AR * 32;
    _Float16* sB = Bs + w * 1024;

    for (int k0 = 0; k0 < K; k0 += 32) {
#pragma unroll
        for (int u = 0; u < TM / 64; ++u)
            GLDS16(gA + (size_t)u * 16 * K + k0, sA + u * 512);
        GLDS16(gB + k0,          sB);
        GLDS16(gB + 16 * K + k0, sB + 512);
        __syncthreads();

        f16x8 af[TI], bf[4];
        const int pa = (q4 ^ SWZ4(a)) << 3;
#pragma unroll
        for (int i = 0; i < TI; ++i)
            af[i] = *(const f16x8*)&As[(wm + 16 * i + a) * 32 + pa];
#pragma unroll
        for (int j = 0; j < 4; ++j)
            bf[j] = *(const f16x8*)&Bs[(wn + 16 * j + a) * 32 + pa];
#pragma unroll
        for (int i = 0; i < TI; ++i)
#pragma unroll
            for (int j = 0; j < 4; ++j)
                acc[i][j] = MFMA16(af[i], bf[j], acc[i][j]);
        __syncthreads();   // last iter: all frag reads drained -> SMEM reusable
    }

    if (EPI == 0) {
        const int nbase = n0 + wn;                 // 64-aligned -> one (t,h)
        const int t = nbase >> 10, h = (nbase >> 6) & 15;
        const int bb = (m0 + wm) >> 11;
        const int sbase = (m0 + wm) & 2047;        // 64-aligned
        _Float16* base = (_Float16*)Cout;
        _Float16* Cw = (_Float16*)SMEM + w * 2304; // 32 rows x 72 f16 (private)
        const int lsub = l >> 3, c = l & 7;
        if (t != 2) {
            const int cswz = (t == 1) ? (c ^ lsub) : c;   // k: chunk^(s&7)
            _Float16* gq = base + (size_t)t * HBUF
                         + ((size_t)(bb * 16 + h) * 2048 + sbase) * 64;
#pragma unroll
            for (int pass = 0; pass < 2; ++pass) {
#pragma unroll
                for (int j = 0; j < 4; ++j) {
                    const float bv = bias[nbase + 16 * j + a];
#pragma unroll
                    for (int i2 = 0; i2 < 2; ++i2)
#pragma unroll
                        for (int r = 0; r < 4; ++r)
                            Cw[(16 * i2 + q4 * 4 + r) * 72 + 16 * j + a] =
                                (_Float16)(acc[2 * pass + i2][j][r] + bv);
                }
                // wave-private slice: per-wave in-order DS => no barrier
#pragma unroll
                for (int pp = 0; pp < 4; ++pp) {
                    const int lr = pp * 8 + lsub;
                    f16x8 v8 = *(const f16x8*)&Cw[lr * 72 + cswz * 8];
                    *(f16x8*)(gq + (size_t)(32 * pass + lr) * 64 + c * 8) = v8;
                }
            }
        } else {
            // transposed image [d][s] -> swizzled vT rows (chunk^(d&7))
            const int cswz = c ^ lsub;
            _Float16* gv = base + 2 * HBUF
                         + ((size_t)(bb * 16 + h) * 64) * 2048 + sbase;
#pragma unroll
            for (int pass = 0; pass < 2; ++pass) {
#pragma unroll
                for (int jj = 0; jj < 2; ++jj) {
                    const int j = 2 * pass + jj;
                    const float bv = bias[nbase + 16 * j + a];
#pragma unroll
                    for (int i = 0; i < 4; ++i) {
                        f16x4 pk;
#pragma unroll
                        for (int r = 0; r < 4; ++r)
                            pk[r] = (_Float16)(acc[i][j][r] + bv);
                        *(f16x4*)&Cw[(16 * jj + a) * 72 + 16 * i + q4 * 4] = pk;
                    }
                }
#pragma unroll
                for (int pp = 0; pp < 4; ++pp) {
                    const int dl = pp * 8 + lsub;
                    f16x8 v8 = *(const f16x8*)&Cw[dl * 72 + cswz * 8];
                    *(f16x8*)(gv + (size_t)(32 * pass + dl) * 2048 + c * 8) = v8;
                }
            }
        }
    } else {
        float* C = (float*)Cout;
        float* Cw = (float*)SMEM + w * 1088;       // 16 rows x 68 fp32 (private)
        const int lr = l >> 2, lc = l & 3;
#pragma unroll
        for (int i = 0; i < TI; ++i) {
#pragma unroll
            for (int j = 0; j < 4; ++j) {
                const float bv = bias[n0 + wn + 16 * j + a];
#pragma unroll
                for (int r = 0; r < 4; ++r)
                    Cw[(q4 * 4 + r) * 68 + 16 * j + a] = acc[i][j][r] + bv;
            }
            float* gout = C + (size_t)(m0 + wm + 16 * i + lr) * N + n0 + wn;
#pragma unroll
            for (int pp = 0; pp < 4; ++pp) {
                float4 v4 = *(const float4*)&Cw[lr * 68 + (lc + 4 * pp) * 4];
                *(float4*)(gout + (lc + 4 * pp) * 4) = v4;
            }
        }
    }
}

// ---------------------------------------------------------------------------
// Paired-tile flash attention, no-max softmax, 1 barrier/tile.
// R8: V-fragment reads shared across the hi/lo pair (both P's register-
// resident before the PV loop; lo's P overwrites the wave slice only after
// hi's P was read -- per-wave DS ops are in-order).
// ---------------------------------------------------------------------------
__global__ __launch_bounds__(256, 2) void attn_mfma(
    const _Float16* __restrict__ qb, const _Float16* __restrict__ kb,
    const _Float16* __restrict__ vtb, _Float16* __restrict__ ctx)
{
    __shared__ _Float16 Ks[2][64 * 64];
    __shared__ _Float16 VT[2][64 * 64];
    __shared__ _Float16 Ps[4][16 * 64];

    const int bid = blockIdx.x;
    const int jj = bid >> 3;
    const int bhIdx = (bid & 7) * 4 + (jj >> 4);   // 0..31
    const int p = jj & 15;
    const int b = bhIdx >> 4, h = bhIdx & 15;
    const int tid = threadIdx.x;
    const int w = tid >> 6, l = tid & 63;
    const int a = l & 15, q4 = l >> 4, a7 = a & 7;
    const size_t bh  = ((size_t)b * NHEAD + h) * SEQ;
    const size_t bhd = ((size_t)b * NHEAD + h) * 64;

    const int qHi = (31 - p) * 64 + w * 16;
    const int qLo = p * 64 + w * 16;
    const int ntiles = 32 - p;

    f16x8 qfh[2], qfl[2];
    {
        const _Float16* qp = qb + (bh + qHi + a) * 64;
        qfh[0] = *(const f16x8*)(qp + q4 * 8);
        qfh[1] = *(const f16x8*)(qp + 32 + q4 * 8);
        const _Float16* ql = qb + (bh + qLo + a) * 64;
        qfl[0] = *(const f16x8*)(ql + q4 * 8);
        qfl[1] = *(const f16x8*)(ql + 32 + q4 * 8);
    }

    f32x4 Oh[4], Ol[4];
#pragma unroll
    for (int c = 0; c < 4; ++c) {
        Oh[c] = (f32x4){0.f, 0.f, 0.f, 0.f};
        Ol[c] = (f32x4){0.f, 0.f, 0.f, 0.f};
    }
    float lh = 0.f, ll = 0.f;

    const _Float16* kg = kb + (bh + w * 16) * 64 + l * 8;
    const int vrow = w * 16 + (l >> 3);
    const _Float16* vg = vtb + (bhd + vrow) * 2048 + (l & 7) * 8;
    _Float16* pbuf = &Ps[w][0];
    const int p0 = (q4 ^ a7) << 3;

    auto stage = [&](int t, int buf) {
        _Float16* ksl = &Ks[buf][0] + w * 1024 + l * 8;
        const _Float16* kt = kg + (size_t)t * 4096;
        GLDS16(kt,       ksl);
        GLDS16(kt + 512, ksl + 512);
        _Float16* vtl = &VT[buf][0] + vrow * 64 + (l & 7) * 8;
        GLDS16(vg + t * 64,            vtl);
        GLDS16(vg + t * 64 + 8 * 2048, vtl + 512);
    };

    stage(0, 0);

    for (int t = 0; t < ntiles; ++t) {
        __syncthreads();                 // tile t landed; prev-iter LDS reads drained
        if (t + 1 < ntiles) stage(t + 1, (t + 1) & 1);

        const _Float16* ksb  = &Ks[t & 1][0];
        const _Float16* vbuf = &VT[t & 1][0];
        const int kt0 = t * 64;
        const bool doLo = (t <= p);

        f32x4 sh[4], sl[4];
#pragma unroll
        for (int n0 = 0; n0 < 4; ++n0) {
            f16x8 kf0 = *(const f16x8*)&ksb[(n0 * 16 + a) * 64 + p0];
            f16x8 kf1 = *(const f16x8*)&ksb[(n0 * 16 + a) * 64 + (p0 ^ 32)];
            f32x4 c = (f32x4){0.f, 0.f, 0.f, 0.f};
            c = MFMA16(kf0, qfh[0], c);
            c = MFMA16(kf1, qfh[1], c);
            sh[n0] = c;
            if (doLo) {
                f32x4 d = (f32x4){0.f, 0.f, 0.f, 0.f};
                d = MFMA16(kf0, qfl[0], d);
                d = MFMA16(kf1, qfl[1], d);
                sl[n0] = d;
            }
        }

        // softmax + P-write + P-readback (register-resident fragments)
        auto softmax_P = [&](f32x4 st[4], float& lrun, const bool maskT,
                             const int qbase, f16x8& pf0, f16x8& pf1) {
            if (maskT) {
#pragma unroll
                for (int n0 = 0; n0 < 4; ++n0)
#pragma unroll
                    for (int r = 0; r < 4; ++r) {
                        const int kgl = kt0 + n0 * 16 + q4 * 4 + r;
                        st[n0][r] = (kgl > qbase + a) ? MASK2
                                                      : fmaf(st[n0][r], SCALE2, BIAS2);
                    }
            } else {
#pragma unroll
                for (int n0 = 0; n0 < 4; ++n0)
#pragma unroll
                    for (int r = 0; r < 4; ++r)
                        st[n0][r] = fmaf(st[n0][r], SCALE2, BIAS2);
            }
            float ls = 0.f;
#pragma unroll
            for (int n0 = 0; n0 < 4; ++n0)
#pragma unroll
                for (int r = 0; r < 4; ++r) {
                    const float pe = EXP2F(st[n0][r]);
                    st[n0][r] = pe;
                    ls += pe;
                }
            lrun += ls;
#pragma unroll
            for (int n0 = 0; n0 < 4; ++n0) {
                f16x4 pk;
#pragma unroll
                for (int r = 0; r < 4; ++r) pk[r] = (_Float16)st[n0][r];
                const int pos = (2 * n0 + (q4 >> 1)) ^ a7;
                *(f16x4*)&pbuf[a * 64 + pos * 8 + ((q4 & 1) << 2)] = pk;
            }
            pf0 = *(const f16x8*)&pbuf[a * 64 + p0];
            pf1 = *(const f16x8*)&pbuf[a * 64 + (p0 ^ 32)];
        };

        f16x8 pfh0, pfh1, pfl0, pfl1;
        softmax_P(sh, lh, t == 31 - p, qHi, pfh0, pfh1);
        if (doLo) softmax_P(sl, ll, t == p, qLo, pfl0, pfl1);

        // PV: one V-fragment read feeds both halves
#pragma unroll
        for (int c = 0; c < 4; ++c) {
            f16x8 vf0 = *(const f16x8*)&vbuf[(c * 16 + a) * 64 + p0];
            f16x8 vf1 = *(const f16x8*)&vbuf[(c * 16 + a) * 64 + (p0 ^ 32)];
            Oh[c] = MFMA16(vf0, pfh0, Oh[c]);
            Oh[c] = MFMA16(vf1, pfh1, Oh[c]);
            if (doLo) {
                Ol[c] = MFMA16(vf0, pfl0, Ol[c]);
                Ol[c] = MFMA16(vf1, pfl1, Ol[c]);
            }
        }
    }

    // ---- epilogue: reduce l, normalize, store ctx fp16 with SWZ4 GEMM-A swizzle
    auto finish = [&](float lrun, const f32x4* O, const int qbase) {
        float lt = lrun;
        lt += __shfl_xor(lt, 16);
        lt += __shfl_xor(lt, 32);
        const float inv = 1.0f / lt;
        const size_t row = (size_t)b * SEQ + qbase + a;
#pragma unroll
        for (int c = 0; c < 4; ++c) {
            const int d0 = c * 16 + q4 * 4;
            const int kcol = h * 64 + (d0 & ~31)
                           + ((((d0 >> 3) & 3) ^ SWZ4(a)) << 3) + (d0 & 7);
            f16x4 ov;
#pragma unroll
            for (int r = 0; r < 4; ++r) ov[r] = (_Float16)(O[c][r] * inv);
            *(f16x4*)(ctx + row * HID + kcol) = ov;
        }
    };
    finish(lh, Oh, qHi);
    finish(ll, Ol, qLo);
}

// ---------------------------------------------------------------------------
// WS: [A_h][WqkvT][WdT][q | k(sw) | vT(sw)][ctx]  (all fp16, 50.3 MB)
// ---------------------------------------------------------------------------
extern "C" void kernel_launch(void* const* d_in, const int* in_sizes, int n_in,
                              void* d_out, int out_size, void* d_ws, size_t ws_size,
                              hipStream_t stream) {
    const float* hs   = (const float*)d_in[0];
    const float* Wqkv = (const float*)d_in[2];
    const float* bqkv = (const float*)d_in[3];
    const float* Wd   = (const float*)d_in[4];
    const float* bd   = (const float*)d_in[5];

    _Float16* A_h   = (_Float16*)d_ws;
    _Float16* WqkvT = A_h + (size_t)MTOT * HID;
    _Float16* WdT   = WqkvT + (size_t)QKVN * HID;
    _Float16* qbuf  = WdT + (size_t)HID * HID;            // q | k(sw) | vT(sw)
    _Float16* ctxb  = qbuf + 3 * HBUF;

    prep_kernel<<<6144, 256, 0, stream>>>(hs, Wqkv, Wd, A_h, WqkvT, WdT);

    mfma_gemm<0, 128><<<dim3(QKVN / 128, MTOT / 128), 256, 0, stream>>>(
        A_h, WqkvT, bqkv, (void*)qbuf, MTOT, QKVN, HID);

    attn_mfma<<<512, 256, 0, stream>>>(
        qbuf, qbuf + HBUF, qbuf + 2 * HBUF, ctxb);

    mfma_gemm<1, 64><<<dim3(HID / 128, MTOT / 64), 256, 0, stream>>>(
        ctxb, WdT, bd, d_out, MTOT, HID, HID);
}

// Round 9
// 197.676 us; speedup vs baseline: 1.0408x; 1.0408x over previous
//
#include <hip/hip_runtime.h>
#include <math.h>

#define BATCH 2
#define SEQ   2048
#define HID   1024
#define NHEAD 16
#define HDIM  64
#define MTOT  (BATCH * SEQ)   // 4096
#define QKVN  (3 * HID)       // 3072
#define HBUF  ((size_t)BATCH * NHEAD * SEQ * HDIM)   // elems per q/k/vT buf

typedef _Float16 f16x8 __attribute__((ext_vector_type(8)));
typedef _Float16 f16x4 __attribute__((ext_vector_type(4)));
typedef float    f32x4 __attribute__((ext_vector_type(4)));

#define MFMA16(a, b, c) __builtin_amdgcn_mfma_f32_16x16x32_f16((a), (b), (c), 0, 0, 0)

#define GLDS16(gp, lp) __builtin_amdgcn_global_load_lds( \
    (const __attribute__((address_space(1))) void*)(gp), \
    (__attribute__((address_space(3))) void*)(lp), 16, 0, 0)

#if __has_builtin(__builtin_amdgcn_exp2f)
#define EXP2F(x) __builtin_amdgcn_exp2f(x)
#else
#define EXP2F(x) exp2f(x)
#endif

#define SCALE2 0.18033688011f     // 0.125 * log2(e)
#define MASK2  -14426.950408f     // -10000 * log2(e)  -> exp2 == 0 exactly
#define BIAS2  -4.0f              // headroom shift; cancels in normalization

// two-bit chunk swizzle for the B-operand LDS image
#define SWZ4(row) (((row) & 3) ^ (((row) >> 2) & 3))

// ---------------------------------------------------------------------------
// Fragment-order A layout (K=1024, 32 k32-groups):
//   elem (m,k) -> A[ ((m>>4)*32 + (k>>5))*512 + ((k>>3)&3)*128 + (m&15)*8 + (k&7) ]
// so MFMA lane l = q4*16+a reads its 16B fragment at ((m16*32+k32)*64 + l)*8.
// ---------------------------------------------------------------------------

// ---------------------------------------------------------------------------
// Fused prep:
//   blocks [0,256):     hs fp32 -> fp16 in FRAGMENT ORDER (LDS-bounced, both
//                       global read and write fully coalesced)
//   blocks [256,4352):  Wqkv/Wd fp32 [K][N] -> fp16 [N][K] + SWZ4 B swizzle
// ---------------------------------------------------------------------------
__global__ __launch_bounds__(256) void prep_kernel(
    const float* __restrict__ hs, const float* __restrict__ Wqkv,
    const float* __restrict__ Wd, _Float16* __restrict__ A_h,
    _Float16* __restrict__ outQ, _Float16* __restrict__ outD)
{
    __shared__ __align__(16) _Float16 LB[16 * 1040];   // 33.3 KB
    const int gid = blockIdx.x;
    const int tid = threadIdx.x;
    if (gid < 256) {
        const int m16 = gid;
        // pass 1: coalesced read + convert -> row-major LDS (stride 1040)
#pragma unroll
        for (int p = 0; p < 8; ++p) {
            const int task = p * 256 + tid;
            const int row = task >> 7, cc = task & 127;
            const float* src = hs + ((size_t)m16 * 16 + row) * 1024 + cc * 8;
            f16x8 o;
#pragma unroll
            for (int j = 0; j < 8; ++j) o[j] = (_Float16)src[j];
            *(f16x8*)&LB[row * 1040 + cc * 8] = o;
        }
        __syncthreads();
        // pass 2: gather fragments (stride-1040 ~ 2 groups mod 8 -> uniform
        // bank load), write contiguous 16B/lane
        _Float16* dst = A_h + (size_t)m16 * 16384;
#pragma unroll
        for (int p = 0; p < 8; ++p) {
            const int ci = p * 256 + tid;
            const int k32 = ci >> 6, lane = ci & 63;
            const int aa = lane & 15, qq = lane >> 4;
            f16x8 v = *(const f16x8*)&LB[aa * 1040 + (k32 * 4 + qq) * 8];
            *(f16x8*)(dst + (size_t)ci * 8) = v;
        }
        return;
    }
    // ---- weights: [K][N] -> [N][K] transpose-convert + SWZ4 chunk swizzle
    _Float16 (*T)[36] = (_Float16(*)[36])LB;
    const int tb = gid - 256;
    const int bx = tb & 127, k0 = (tb >> 7) * 32;
    const float* in;
    _Float16* out;
    int N, n0;
    if (bx < 96) { in = Wqkv; out = outQ; N = QKVN; n0 = bx * 32; }
    else         { in = Wd;   out = outD; N = HID;  n0 = (bx - 96) * 32; }
    {
        const int r = tid >> 3, c4 = (tid & 7) * 4;
        float4 v = *(const float4*)(in + (size_t)(k0 + r) * N + n0 + c4);
        T[r][c4 + 0] = (_Float16)v.x;
        T[r][c4 + 1] = (_Float16)v.y;
        T[r][c4 + 2] = (_Float16)v.z;
        T[r][c4 + 3] = (_Float16)v.w;
    }
    __syncthreads();
    {
        const int nn = tid >> 3, k4 = (tid & 7) * 4;
        const int n = n0 + nn;
        f16x4 o;
        o[0] = T[k4 + 0][nn]; o[1] = T[k4 + 1][nn];
        o[2] = T[k4 + 2][nn]; o[3] = T[k4 + 3][nn];
        const int pos = ((k4 >> 3) ^ SWZ4(n)), half = (k4 >> 2) & 1;
        *(f16x4*)(out + (size_t)n * 1024 + k0 + pos * 8 + half * 4) = o;
    }
}

// ---------------------------------------------------------------------------
// MFMA fp16 GEMM, TMx128xK1024, flatmm-style:
//   A: direct global->VGPR fragment loads (fragment-order layout), no LDS.
//   B: LDS double-buffered GLDS16 staging, ONE barrier per BK32 iter.
//   Prefetch A(t+1)+B(t+1) right after the barrier, compute t underneath.
// LDS-bounce epilogues (reuse Bs region after a barrier):
//   EPI=0 (TM=128): q plain / k chunk^(s&7) / v transposed -> swizzled vT.
//   EPI=1 (TM=64):  plain fp32 [M][N] coalesced float4.
// ---------------------------------------------------------------------------
template<int EPI, int TM>
__global__ __launch_bounds__(256) void mfma_gemm(
    const _Float16* __restrict__ A, const _Float16* __restrict__ Bt,
    const float* __restrict__ bias, void* __restrict__ Cout)
{
    constexpr int SMEM_BYTES = (EPI == 0) ? 18432 : 17408;
    __shared__ __align__(16) char SMEM[SMEM_BYTES];
    _Float16* Bs = (_Float16*)SMEM;            // [2][128*32] = 16 KB
    constexpr int TI = TM / 32;
    constexpr int NI = 32;                     // K/32

    const int tid = threadIdx.x;
    const int w = tid >> 6, l = tid & 63;
    const int a = l & 15, q4 = l >> 4;
    const int m0 = blockIdx.y * TM, n0 = blockIdx.x * 128;
    const int wm = (w >> 1) * (TM / 2), wn = (w & 1) * 64;

    f32x4 acc[TI][4];
#pragma unroll
    for (int i = 0; i < TI; ++i)
#pragma unroll
        for (int j = 0; j < 4; ++j) acc[i][j] = (f32x4){0.f, 0.f, 0.f, 0.f};

    const _Float16* gB = Bt + (size_t)(n0 + w * 32 + (l >> 2)) * 1024 + (l & 3) * 8;
    const _Float16* gA = A + ((size_t)((m0 + wm) >> 4) * 32) * 512 + l * 8;

    auto stageB = [&](int t) {
        _Float16* sB = Bs + ((t & 1) << 12) + w * 1024;
        GLDS16(gB + t * 32,          sB);
        GLDS16(gB + 16 * 1024 + t * 32, sB + 512);
    };

    f16x8 afc[TI], afn[TI];
    stageB(0);
#pragma unroll
    for (int i = 0; i < TI; ++i)
        afc[i] = *(const f16x8*)(gA + (size_t)i * 16384);

    for (int t = 0; t < NI; ++t) {
        __syncthreads();                 // B(t)+A(t) landed; prev reads drained
        if (t + 1 < NI) {
#pragma unroll
            for (int i = 0; i < TI; ++i)
                afn[i] = *(const f16x8*)(gA + (size_t)i * 16384 + (t + 1) * 512);
            stageB(t + 1);
        }
        const _Float16* bs = Bs + ((t & 1) << 12);
        f16x8 bf[4];
        const int pa = (q4 ^ SWZ4(a)) << 3;
#pragma unroll
        for (int j = 0; j < 4; ++j)
            bf[j] = *(const f16x8*)&bs[(wn + 16 * j + a) * 32 + pa];
#pragma unroll
        for (int i = 0; i < TI; ++i)
#pragma unroll
            for (int j = 0; j < 4; ++j)
                acc[i][j] = MFMA16(afc[i], bf[j], acc[i][j]);
#pragma unroll
        for (int i = 0; i < TI; ++i) afc[i] = afn[i];
    }
    __syncthreads();                     // all B reads drained -> SMEM reusable

    if (EPI == 0) {
        const int nbase = n0 + wn;                 // 64-aligned -> one (t,h)
        const int t = nbase >> 10, h = (nbase >> 6) & 15;
        const int bb = (m0 + wm) >> 11;
        const int sbase = (m0 + wm) & 2047;        // 64-aligned
        _Float16* base = (_Float16*)Cout;
        _Float16* Cw = (_Float16*)SMEM + w * 2304; // 32 rows x 72 f16 (private)
        const int lsub = l >> 3, c = l & 7;
        if (t != 2) {
            const int cswz = (t == 1) ? (c ^ lsub) : c;   // k: chunk^(s&7)
            _Float16* gq = base + (size_t)t * HBUF
                         + ((size_t)(bb * 16 + h) * 2048 + sbase) * 64;
#pragma unroll
            for (int pass = 0; pass < 2; ++pass) {
#pragma unroll
                for (int j = 0; j < 4; ++j) {
                    const float bv = bias[nbase + 16 * j + a];
#pragma unroll
                    for (int i2 = 0; i2 < 2; ++i2)
#pragma unroll
                        for (int r = 0; r < 4; ++r)
                            Cw[(16 * i2 + q4 * 4 + r) * 72 + 16 * j + a] =
                                (_Float16)(acc[2 * pass + i2][j][r] + bv);
                }
                // wave-private slice: per-wave in-order DS => no barrier
#pragma unroll
                for (int pp = 0; pp < 4; ++pp) {
                    const int lr = pp * 8 + lsub;
                    f16x8 v8 = *(const f16x8*)&Cw[lr * 72 + cswz * 8];
                    *(f16x8*)(gq + (size_t)(32 * pass + lr) * 64 + c * 8) = v8;
                }
            }
        } else {
            // transposed image [d][s] -> swizzled vT rows (chunk^(d&7))
            const int cswz = c ^ lsub;
            _Float16* gv = base + 2 * HBUF
                         + ((size_t)(bb * 16 + h) * 64) * 2048 + sbase;
#pragma unroll
            for (int pass = 0; pass < 2; ++pass) {
#pragma unroll
                for (int jj = 0; jj < 2; ++jj) {
                    const int j = 2 * pass + jj;
                    const float bv = bias[nbase + 16 * j + a];
#pragma unroll
                    for (int i = 0; i < 4; ++i) {
                        f16x4 pk;
#pragma unroll
                        for (int r = 0; r < 4; ++r)
                            pk[r] = (_Float16)(acc[i][j][r] + bv);
                        *(f16x4*)&Cw[(16 * jj + a) * 72 + 16 * i + q4 * 4] = pk;
                    }
                }
#pragma unroll
                for (int pp = 0; pp < 4; ++pp) {
                    const int dl = pp * 8 + lsub;
                    f16x8 v8 = *(const f16x8*)&Cw[dl * 72 + cswz * 8];
                    *(f16x8*)(gv + (size_t)(32 * pass + dl) * 2048 + c * 8) = v8;
                }
            }
        }
    } else {
        float* C = (float*)Cout;
        float* Cw = (float*)SMEM + w * 1088;       // 16 rows x 68 fp32 (private)
        const int lr = l >> 2, lc = l & 3;
#pragma unroll
        for (int i = 0; i < TI; ++i) {
#pragma unroll
            for (int j = 0; j < 4; ++j) {
                const float bv = bias[n0 + wn + 16 * j + a];
#pragma unroll
                for (int r = 0; r < 4; ++r)
                    Cw[(q4 * 4 + r) * 68 + 16 * j + a] = acc[i][j][r] + bv;
            }
            float* gout = C + (size_t)(m0 + wm + 16 * i + lr) * HID + n0 + wn;
#pragma unroll
            for (int pp = 0; pp < 4; ++pp) {
                float4 v4 = *(const float4*)&Cw[lr * 68 + (lc + 4 * pp) * 4];
                *(float4*)(gout + (lc + 4 * pp) * 4) = v4;
            }
        }
    }
}

// ---------------------------------------------------------------------------
// Paired-tile flash attention, no-max softmax, 1 barrier/tile (R8 core).
// R9: epilogue writes ctx in gemm2's FRAGMENT-ORDER A layout.
// ---------------------------------------------------------------------------
__global__ __launch_bounds__(256, 2) void attn_mfma(
    const _Float16* __restrict__ qb, const _Float16* __restrict__ kb,
    const _Float16* __restrict__ vtb, _Float16* __restrict__ ctx)
{
    __shared__ _Float16 Ks[2][64 * 64];
    __shared__ _Float16 VT[2][64 * 64];
    __shared__ _Float16 Ps[4][16 * 64];

    const int bid = blockIdx.x;
    const int jj = bid >> 3;
    const int bhIdx = (bid & 7) * 4 + (jj >> 4);   // 0..31
    const int p = jj & 15;
    const int b = bhIdx >> 4, h = bhIdx & 15;
    const int tid = threadIdx.x;
    const int w = tid >> 6, l = tid & 63;
    const int a = l & 15, q4 = l >> 4, a7 = a & 7;
    const size_t bh  = ((size_t)b * NHEAD + h) * SEQ;
    const size_t bhd = ((size_t)b * NHEAD + h) * 64;

    const int qHi = (31 - p) * 64 + w * 16;
    const int qLo = p * 64 + w * 16;
    const int ntiles = 32 - p;

    f16x8 qfh[2], qfl[2];
    {
        const _Float16* qp = qb + (bh + qHi + a) * 64;
        qfh[0] = *(const f16x8*)(qp + q4 * 8);
        qfh[1] = *(const f16x8*)(qp + 32 + q4 * 8);
        const _Float16* ql = qb + (bh + qLo + a) * 64;
        qfl[0] = *(const f16x8*)(ql + q4 * 8);
        qfl[1] = *(const f16x8*)(ql + 32 + q4 * 8);
    }

    f32x4 Oh[4], Ol[4];
#pragma unroll
    for (int c = 0; c < 4; ++c) {
        Oh[c] = (f32x4){0.f, 0.f, 0.f, 0.f};
        Ol[c] = (f32x4){0.f, 0.f, 0.f, 0.f};
    }
    float lh = 0.f, ll = 0.f;

    const _Float16* kg = kb + (bh + w * 16) * 64 + l * 8;
    const int vrow = w * 16 + (l >> 3);
    const _Float16* vg = vtb + (bhd + vrow) * 2048 + (l & 7) * 8;
    _Float16* pbuf = &Ps[w][0];
    const int p0 = (q4 ^ a7) << 3;

    auto stage = [&](int t, int buf) {
        _Float16* ksl = &Ks[buf][0] + w * 1024 + l * 8;
        const _Float16* kt = kg + (size_t)t * 4096;
        GLDS16(kt,       ksl);
        GLDS16(kt + 512, ksl + 512);
        _Float16* vtl = &VT[buf][0] + vrow * 64 + (l & 7) * 8;
        GLDS16(vg + t * 64,            vtl);
        GLDS16(vg + t * 64 + 8 * 2048, vtl + 512);
    };

    stage(0, 0);

    for (int t = 0; t < ntiles; ++t) {
        __syncthreads();                 // tile t landed; prev-iter LDS reads drained
        if (t + 1 < ntiles) stage(t + 1, (t + 1) & 1);

        const _Float16* ksb  = &Ks[t & 1][0];
        const _Float16* vbuf = &VT[t & 1][0];
        const int kt0 = t * 64;
        const bool doLo = (t <= p);

        f32x4 sh[4], sl[4];
#pragma unroll
        for (int n0 = 0; n0 < 4; ++n0) {
            f16x8 kf0 = *(const f16x8*)&ksb[(n0 * 16 + a) * 64 + p0];
            f16x8 kf1 = *(const f16x8*)&ksb[(n0 * 16 + a) * 64 + (p0 ^ 32)];
            f32x4 c = (f32x4){0.f, 0.f, 0.f, 0.f};
            c = MFMA16(kf0, qfh[0], c);
            c = MFMA16(kf1, qfh[1], c);
            sh[n0] = c;
            if (doLo) {
                f32x4 d = (f32x4){0.f, 0.f, 0.f, 0.f};
                d = MFMA16(kf0, qfl[0], d);
                d = MFMA16(kf1, qfl[1], d);
                sl[n0] = d;
            }
        }

        auto softmax_P = [&](f32x4 st[4], float& lrun, const bool maskT,
                             const int qbase, f16x8& pf0, f16x8& pf1) {
            if (maskT) {
#pragma unroll
                for (int n0 = 0; n0 < 4; ++n0)
#pragma unroll
                    for (int r = 0; r < 4; ++r) {
                        const int kgl = kt0 + n0 * 16 + q4 * 4 + r;
                        st[n0][r] = (kgl > qbase + a) ? MASK2
                                                      : fmaf(st[n0][r], SCALE2, BIAS2);
                    }
            } else {
#pragma unroll
                for (int n0 = 0; n0 < 4; ++n0)
#pragma unroll
                    for (int r = 0; r < 4; ++r)
                        st[n0][r] = fmaf(st[n0][r], SCALE2, BIAS2);
            }
            float ls = 0.f;
#pragma unroll
            for (int n0 = 0; n0 < 4; ++n0)
#pragma unroll
                for (int r = 0; r < 4; ++r) {
                    const float pe = EXP2F(st[n0][r]);
                    st[n0][r] = pe;
                    ls += pe;
                }
            lrun += ls;
#pragma unroll
            for (int n0 = 0; n0 < 4; ++n0) {
                f16x4 pk;
#pragma unroll
                for (int r = 0; r < 4; ++r) pk[r] = (_Float16)st[n0][r];
                const int pos = (2 * n0 + (q4 >> 1)) ^ a7;
                *(f16x4*)&pbuf[a * 64 + pos * 8 + ((q4 & 1) << 2)] = pk;
            }
            pf0 = *(const f16x8*)&pbuf[a * 64 + p0];
            pf1 = *(const f16x8*)&pbuf[a * 64 + (p0 ^ 32)];
        };

        f16x8 pfh0, pfh1, pfl0, pfl1;
        softmax_P(sh, lh, t == 31 - p, qHi, pfh0, pfh1);
        if (doLo) softmax_P(sl, ll, t == p, qLo, pfl0, pfl1);

        // PV: one V-fragment read feeds both halves
#pragma unroll
        for (int c = 0; c < 4; ++c) {
            f16x8 vf0 = *(const f16x8*)&vbuf[(c * 16 + a) * 64 + p0];
            f16x8 vf1 = *(const f16x8*)&vbuf[(c * 16 + a) * 64 + (p0 ^ 32)];
            Oh[c] = MFMA16(vf0, pfh0, Oh[c]);
            Oh[c] = MFMA16(vf1, pfh1, Oh[c]);
            if (doLo) {
                Ol[c] = MFMA16(vf0, pfl0, Ol[c]);
                Ol[c] = MFMA16(vf1, pfl1, Ol[c]);
            }
        }
    }

    // ---- epilogue: reduce l, normalize, store ctx in FRAGMENT-ORDER layout
    auto finish = [&](float lrun, const f32x4* O, const int qbase) {
        float lt = lrun;
        lt += __shfl_xor(lt, 16);
        lt += __shfl_xor(lt, 32);
        const float inv = 1.0f / lt;
        const int m16 = (b * SEQ + qbase) >> 4;      // qbase is 16-aligned
        _Float16* dst = ctx + (size_t)m16 * 16384;
#pragma unroll
        for (int c = 0; c < 4; ++c) {
            const int k32   = h * 2 + (c >> 1);
            const int lanep = ((c & 1) * 2 + (q4 >> 1)) * 16 + a;
            const int j0    = (q4 & 1) * 4;
            f16x4 ov;
#pragma unroll
            for (int r = 0; r < 4; ++r) ov[r] = (_Float16)(O[c][r] * inv);
            *(f16x4*)(dst + ((size_t)k32 * 64 + lanep) * 8 + j0) = ov;
        }
    };
    finish(lh, Oh, qHi);
    finish(ll, Ol, qLo);
}

// ---------------------------------------------------------------------------
// WS: [A_h frag][WqkvT][WdT][q | k(sw) | vT(sw)][ctx frag]  (fp16, 50.3 MB)
// ---------------------------------------------------------------------------
extern "C" void kernel_launch(void* const* d_in, const int* in_sizes, int n_in,
                              void* d_out, int out_size, void* d_ws, size_t ws_size,
                              hipStream_t stream) {
    const float* hs   = (const float*)d_in[0];
    const float* Wqkv = (const float*)d_in[2];
    const float* bqkv = (const float*)d_in[3];
    const float* Wd   = (const float*)d_in[4];
    const float* bd   = (const float*)d_in[5];

    _Float16* A_h   = (_Float16*)d_ws;
    _Float16* WqkvT = A_h + (size_t)MTOT * HID;
    _Float16* WdT   = WqkvT + (size_t)QKVN * HID;
    _Float16* qbuf  = WdT + (size_t)HID * HID;            // q | k(sw) | vT(sw)
    _Float16* ctxb  = qbuf + 3 * HBUF;

    prep_kernel<<<4352, 256, 0, stream>>>(hs, Wqkv, Wd, A_h, WqkvT, WdT);

    mfma_gemm<0, 128><<<dim3(QKVN / 128, MTOT / 128), 256, 0, stream>>>(
        A_h, WqkvT, bqkv, (void*)qbuf);

    attn_mfma<<<512, 256, 0, stream>>>(
        qbuf, qbuf + HBUF, qbuf + 2 * HBUF, ctxb);

    mfma_gemm<1, 64><<<dim3(HID / 128, MTOT / 64), 256, 0, stream>>>(
        ctxb, WdT, bd, d_out);
}